// Round 1
// baseline (43.314 us; speedup 1.0000x reference)
//
#include <hip/hip_runtime.h>
#include <math.h>

// Problem dims (fixed by setup_inputs): B=8, C=128, M=16, H=W=128
#define NB 8
#define NC 128
#define NM 16
#define HW (128*128)   // 16384 spatial positions

// ---------------------------------------------------------------------------
// Kernel 1: pack the 15 mask planes (m=1..15, skip_zero) into one bitmask
// word per (b, pos).  packed[b*HW + pos] bit (m-1) = (masks[b,m,pos] != 0).
// Reads 7.5 MiB (coalesced per-plane), writes 512 KB into d_ws.
// ---------------------------------------------------------------------------
__global__ __launch_bounds__(256) void pack_masks_k(
        const int* __restrict__ masks, unsigned int* __restrict__ packed) {
    int idx = blockIdx.x * blockDim.x + threadIdx.x;   // over NB*HW = 131072
    if (idx >= NB * HW) return;
    int b   = idx >> 14;          // / 16384
    int pos = idx & (HW - 1);
    const int* mb = masks + (size_t)b * NM * HW + pos;
    unsigned int bits = 0u;
    #pragma unroll
    for (int m = 1; m < NM; ++m) {
        bits |= (mb[(size_t)m * HW] != 0 ? 1u : 0u) << (m - 1);
    }
    packed[idx] = bits;
}

// ---------------------------------------------------------------------------
// Kernel 2: one block per (b, c).  Each thread strides over the 16384
// positions with float4/uint4 loads, keeping acc[15] maxes in registers.
// Wave shfl_xor reduce, then 4-wave LDS reduce, direct store of out[b,c,m].
// Output layout [B, C, 15, 1] row-major: out[(b*NC + c)*15 + m].
// ---------------------------------------------------------------------------
__global__ __launch_bounds__(256) void region_max_k(
        const float* __restrict__ encoded,
        const unsigned int* __restrict__ packed,
        float* __restrict__ out) {
    int blk = blockIdx.x;              // 0 .. NB*NC-1
    int b = blk >> 7;                  // / 128
    // c = blk & 127 (folded into the pointer below)
    const float4* e4 = (const float4*)(encoded + (size_t)blk * HW);
    const uint4*  p4 = (const uint4*)(packed  + (size_t)b * HW);
    int t = threadIdx.x;

    float acc[15];
    #pragma unroll
    for (int m = 0; m < 15; ++m) acc[m] = -INFINITY;

    // HW/4 = 4096 float4 elements; 256 threads -> 16 iterations each
    #pragma unroll 4
    for (int i = t; i < HW / 4; i += 256) {
        float4 v  = e4[i];
        uint4  bb = p4[i];
        #pragma unroll
        for (int m = 0; m < 15; ++m) {
            unsigned int bit = 1u << m;
            float v0 = (bb.x & bit) ? v.x : -INFINITY;
            float v1 = (bb.y & bit) ? v.y : -INFINITY;
            float v2 = (bb.z & bit) ? v.z : -INFINITY;
            float v3 = (bb.w & bit) ? v.w : -INFINITY;
            acc[m] = fmaxf(acc[m], fmaxf(fmaxf(v0, v1), fmaxf(v2, v3)));
        }
    }

    // 64-lane butterfly reduce per m
    #pragma unroll
    for (int m = 0; m < 15; ++m) {
        float a = acc[m];
        #pragma unroll
        for (int off = 32; off >= 1; off >>= 1)
            a = fmaxf(a, __shfl_xor(a, off, 64));
        acc[m] = a;
    }

    __shared__ float red[4][15];
    int wave = t >> 6;
    int lane = t & 63;
    if (lane == 0) {
        #pragma unroll
        for (int m = 0; m < 15; ++m) red[wave][m] = acc[m];
    }
    __syncthreads();
    if (t < 15) {
        float a = fmaxf(fmaxf(red[0][t], red[1][t]),
                        fmaxf(red[2][t], red[3][t]));
        out[(size_t)blk * 15 + t] = a;
    }
}

extern "C" void kernel_launch(void* const* d_in, const int* in_sizes, int n_in,
                              void* d_out, int out_size, void* d_ws, size_t ws_size,
                              hipStream_t stream) {
    const float* encoded = (const float*)d_in[0];   // [8,128,128,128] f32
    const int*   masks   = (const int*)d_in[1];     // [8,16,128,128] i32
    float*       out     = (float*)d_out;           // [8,128,15,1] f32
    unsigned int* packed = (unsigned int*)d_ws;     // 131072 u32 = 512 KB

    // Pack 15 mask planes -> bitmask per (b, pos)
    pack_masks_k<<<(NB * HW + 255) / 256, 256, 0, stream>>>(masks, packed);
    // One block per (b, c): masked channel max over all positions
    region_max_k<<<NB * NC, 256, 0, stream>>>(encoded, packed, out);
}

// Round 2
// 35.053 us; speedup vs baseline: 1.2357x; 1.2357x over previous
//
#include <hip/hip_runtime.h>
#include <math.h>
#include <stdint.h>

// Problem dims (fixed by setup_inputs): B=8, C=128, M=16, H=W=128
#define NB 8
#define NC 128
#define NM 16
#define HW (128*128)     // 16384 spatial positions
#define NOUTM 15         // output mask channels (skip m=0)
#define CH 4             // channels per block
#define NCT (NC / CH)    // 32 channel tiles
#define PCHUNK 2         // position chunks per (b, ctile)

// ---------------------------------------------------------------------------
// Kernel 1: pack the 15 mask planes (m=1..15) into one bitmask word per
// (b, pos).  packed[b*HW+pos] bit j = (masks[b, j+1, pos] != 0).
// ---------------------------------------------------------------------------
__global__ __launch_bounds__(256) void pack_masks_k(
        const int* __restrict__ masks, unsigned int* __restrict__ packed) {
    int idx = blockIdx.x * blockDim.x + threadIdx.x;   // over NB*HW = 131072
    if (idx >= NB * HW) return;
    int b   = idx >> 14;
    int pos = idx & (HW - 1);
    const int* mb = masks + (size_t)b * NM * HW + pos;
    unsigned int bits = 0u;
    #pragma unroll
    for (int m = 1; m < NM; ++m) {
        bits |= (mb[(size_t)m * HW] != 0 ? 1u : 0u) << (m - 1);
    }
    packed[idx] = bits;
}

// ---------------------------------------------------------------------------
// Kernel 2: block = (chunk, ctile, b); 256 threads.  Each block owns CH=4
// channels over HW/PCHUNK=8192 positions.  Mask sign-extension (bfe) is done
// ONCE per position and shared across the 4 channels; select via bfi idiom;
// two positions combined per v_max3.  Per-wave butterfly reduce, cross-wave
// LDS combine, partials to d_ws.
// ---------------------------------------------------------------------------
__global__ __launch_bounds__(256) void region_partial_k(
        const float* __restrict__ encoded,
        const unsigned int* __restrict__ packed,
        float* __restrict__ partials) {
    int chunk = blockIdx.x;            // 0..PCHUNK-1
    int ctile = blockIdx.y;            // 0..NCT-1
    int b     = blockIdx.z;            // 0..NB-1
    int t     = threadIdx.x;

    const int F4_PER_CHUNK = HW / PCHUNK / 4;     // 2048 float4 per chunk
    const uint4*  bits4  = (const uint4*)(packed + (size_t)b * HW)
                           + (size_t)chunk * F4_PER_CHUNK;
    const float4* e4base = (const float4*)(encoded
                           + ((size_t)b * NC + (size_t)ctile * CH) * HW)
                           + (size_t)chunk * F4_PER_CHUNK;

    float acc[CH][NOUTM];
    #pragma unroll
    for (int ch = 0; ch < CH; ++ch)
        #pragma unroll
        for (int m = 0; m < NOUTM; ++m) acc[ch][m] = -INFINITY;

    const int NI = F4_PER_CHUNK / 256;            // 8 iterations per thread
    for (int g = 0; g < NI; ++g) {
        int i = g * 256 + t;
        uint4  bb = bits4[i];
        float4 v0 = e4base[i + 0 * (HW / 4)];
        float4 v1 = e4base[i + 1 * (HW / 4)];
        float4 v2 = e4base[i + 2 * (HW / 4)];
        float4 v3 = e4base[i + 3 * (HW / 4)];

        // pair (positions 4i+0, 4i+1)
        {
            float a0[CH] = {v0.x, v1.x, v2.x, v3.x};
            float a1[CH] = {v0.y, v1.y, v2.y, v3.y};
            #pragma unroll
            for (int m = 0; m < NOUTM; ++m) {
                uint32_t s0 = (uint32_t)(((int32_t)(bb.x << (31 - m))) >> 31);
                uint32_t s1 = (uint32_t)(((int32_t)(bb.y << (31 - m))) >> 31);
                #pragma unroll
                for (int ch = 0; ch < CH; ++ch) {
                    uint32_t u0 = (s0 & __float_as_uint(a0[ch])) | (~s0 & 0xFF800000u);
                    uint32_t u1 = (s1 & __float_as_uint(a1[ch])) | (~s1 & 0xFF800000u);
                    acc[ch][m] = fmaxf(fmaxf(acc[ch][m], __uint_as_float(u0)),
                                       __uint_as_float(u1));
                }
            }
        }
        // pair (positions 4i+2, 4i+3)
        {
            float a0[CH] = {v0.z, v1.z, v2.z, v3.z};
            float a1[CH] = {v0.w, v1.w, v2.w, v3.w};
            #pragma unroll
            for (int m = 0; m < NOUTM; ++m) {
                uint32_t s0 = (uint32_t)(((int32_t)(bb.z << (31 - m))) >> 31);
                uint32_t s1 = (uint32_t)(((int32_t)(bb.w << (31 - m))) >> 31);
                #pragma unroll
                for (int ch = 0; ch < CH; ++ch) {
                    uint32_t u0 = (s0 & __float_as_uint(a0[ch])) | (~s0 & 0xFF800000u);
                    uint32_t u1 = (s1 & __float_as_uint(a1[ch])) | (~s1 & 0xFF800000u);
                    acc[ch][m] = fmaxf(fmaxf(acc[ch][m], __uint_as_float(u0)),
                                       __uint_as_float(u1));
                }
            }
        }
    }

    // 64-lane butterfly reduce per (ch, m)
    #pragma unroll
    for (int ch = 0; ch < CH; ++ch)
        #pragma unroll
        for (int m = 0; m < NOUTM; ++m) {
            float a = acc[ch][m];
            #pragma unroll
            for (int off = 32; off >= 1; off >>= 1)
                a = fmaxf(a, __shfl_xor(a, off, 64));
            acc[ch][m] = a;
        }

    __shared__ float red[4][CH * NOUTM];
    int wave = t >> 6;
    int lane = t & 63;
    if (lane == 0) {
        #pragma unroll
        for (int ch = 0; ch < CH; ++ch)
            #pragma unroll
            for (int m = 0; m < NOUTM; ++m)
                red[wave][ch * NOUTM + m] = acc[ch][m];
    }
    __syncthreads();
    if (t < CH * NOUTM) {
        float a = fmaxf(fmaxf(red[0][t], red[1][t]),
                        fmaxf(red[2][t], red[3][t]));
        partials[(((size_t)b * NCT + ctile) * PCHUNK + chunk) * (CH * NOUTM) + t] = a;
    }
}

// ---------------------------------------------------------------------------
// Kernel 3: combine the PCHUNK partials per output.  out[b][c][m][1].
// ---------------------------------------------------------------------------
__global__ __launch_bounds__(256) void finalize_k(
        const float* __restrict__ partials, float* __restrict__ out) {
    int o = blockIdx.x * 256 + threadIdx.x;
    if (o >= NB * NC * NOUTM) return;
    int b = o / (NC * NOUTM);
    int r = o % (NC * NOUTM);
    int c = r / NOUTM;
    int m = r % NOUTM;
    int ctile = c / CH, ci = c % CH;
    size_t base = (((size_t)b * NCT + ctile) * PCHUNK) * (CH * NOUTM)
                  + ci * NOUTM + m;
    float a = partials[base];
    #pragma unroll
    for (int k = 1; k < PCHUNK; ++k)
        a = fmaxf(a, partials[base + (size_t)k * (CH * NOUTM)]);
    out[o] = a;
}

extern "C" void kernel_launch(void* const* d_in, const int* in_sizes, int n_in,
                              void* d_out, int out_size, void* d_ws, size_t ws_size,
                              hipStream_t stream) {
    const float* encoded = (const float*)d_in[0];   // [8,128,128,128] f32
    const int*   masks   = (const int*)d_in[1];     // [8,16,128,128] i32
    float*       out     = (float*)d_out;           // [8,128,15,1] f32

    unsigned int* packed   = (unsigned int*)d_ws;                 // 512 KB
    float*        partials = (float*)d_ws + (size_t)NB * HW;      // 120 KB

    pack_masks_k<<<(NB * HW + 255) / 256, 256, 0, stream>>>(masks, packed);

    dim3 grid2(PCHUNK, NCT, NB);   // 2 x 32 x 8 = 512 blocks
    region_partial_k<<<grid2, 256, 0, stream>>>(encoded, packed, partials);

    finalize_k<<<(NB * NC * NOUTM + 255) / 256, 256, 0, stream>>>(partials, out);
}

// Round 4
// 28.080 us; speedup vs baseline: 1.5425x; 1.2483x over previous
//
#include <hip/hip_runtime.h>
#include <math.h>
#include <stdint.h>

// Problem dims (fixed): B=8, C=128, M=16, H=W=128
#define NB 8
#define NC 128
#define NM 16
#define HW (128*128)       // 16384 positions
#define NOUTM 15
#define CH 8               // channels per block
#define NCT (NC / CH)      // 16 channel tiles
#define PCHUNK 4           // position chunks
#define F4C (HW / PCHUNK / 4)   // 1024 float4 per chunk
#define NINF_PK 0xFC00FC00u     // packed f16 {-inf,-inf}

__device__ __forceinline__ uint32_t pkmax(uint32_t a, uint32_t b) {
    uint32_t d;
    asm("v_pk_max_f16 %0, %1, %2" : "=v"(d) : "v"(a), "v"(b));
    return d;
}
__device__ __forceinline__ uint32_t bfi(uint32_t s, uint32_t a, uint32_t b) {
    uint32_t d;
    asm("v_bfi_b32 %0, %1, %2, %3" : "=v"(d) : "v"(s), "v"(a), "v"(b));
    return d;
}
__device__ __forceinline__ uint32_t cvt_dup(float f) {
    // v_cvt_pkrtz_f16_f32: both halves = f16(f), RTZ (monotonic)
    auto h = __builtin_amdgcn_cvt_pkrtz(f, f);   // __fp16 ext_vector(2)
    return __builtin_bit_cast(uint32_t, h);
}
__device__ __forceinline__ float h2f(uint32_t h16) {
    unsigned short u = (unsigned short)h16;
    __fp16 h = __builtin_bit_cast(__fp16, u);
    return (float)h;
}

// ---------------------------------------------------------------------------
// Kernel 1: pack 15 mask planes into one bitmask word per (b,pos), int4-vec.
// ---------------------------------------------------------------------------
__global__ __launch_bounds__(256) void pack_masks_k(
        const int* __restrict__ masks, uint32_t* __restrict__ packed) {
    int idx = blockIdx.x * 256 + threadIdx.x;   // over NB*HW/4 = 32768
    int b  = idx >> 12;
    int p4 = idx & 4095;
    const int* mb = masks + (size_t)b * NM * HW + (size_t)p4 * 4;
    uint32_t b0 = 0, b1 = 0, b2 = 0, b3 = 0;
    #pragma unroll
    for (int m = 1; m < NM; ++m) {
        int4 mm = *(const int4*)(mb + (size_t)m * HW);
        uint32_t bit = 1u << (m - 1);
        if (mm.x) b0 |= bit;
        if (mm.y) b1 |= bit;
        if (mm.z) b2 |= bit;
        if (mm.w) b3 |= bit;
    }
    *(uint4*)(packed + (size_t)idx * 4) = make_uint4(b0, b1, b2, b3);
}

// ---------------------------------------------------------------------------
// Kernel 2: block=(chunk,ctile,b); 8 channels x 4096 positions per block.
// Packed-f16 accumulators acc[ch][mpair]; bfi select + v_pk_max_f16.
// Mask expansion shared across 8 channels.
// 2-round LDS transpose reduce (conflict-free, 33-word padded rows).
// ---------------------------------------------------------------------------
#define DO_POS(BW, C)                                                         \
    {                                                                         \
        uint32_t vv[8] = {cvt_dup(v0.C), cvt_dup(v1.C), cvt_dup(v2.C),        \
                          cvt_dup(v3.C), cvt_dup(v4.C), cvt_dup(v5.C),        \
                          cvt_dup(v6.C), cvt_dup(v7.C)};                      \
        uint32_t bw_ = (BW);                                                  \
        _Pragma("unroll") for (int mp = 0; mp < 8; ++mp) {                    \
            uint32_t lo = (uint32_t)((int32_t)(bw_ << (31 - 2 * mp)) >> 31);  \
            uint32_t hi = (uint32_t)((int32_t)(bw_ << (30 - 2 * mp)) >> 31);  \
            uint32_t s01 = (lo & 0xFFFFu) | (hi << 16);                       \
            _Pragma("unroll") for (int ch = 0; ch < 8; ++ch) {                \
                acc[ch * 8 + mp] =                                            \
                    pkmax(acc[ch * 8 + mp], bfi(s01, vv[ch], NINF_PK));       \
            }                                                                 \
        }                                                                     \
    }

__global__ __launch_bounds__(256, 2) void region_partial_k(
        const float* __restrict__ encoded,
        const uint32_t* __restrict__ packed,
        float* __restrict__ partials) {
    int chunk = blockIdx.x;            // 0..PCHUNK-1
    int ctile = blockIdx.y;            // 0..NCT-1
    int b     = blockIdx.z;            // 0..NB-1
    int t     = threadIdx.x;

    const uint4*  bits4 = (const uint4*)(packed + (size_t)b * HW)
                          + (size_t)chunk * F4C;
    const float4* e4    = (const float4*)(encoded
                          + ((size_t)b * NC + (size_t)ctile * CH) * HW)
                          + (size_t)chunk * F4C;

    uint32_t acc[64];
    #pragma unroll
    for (int w = 0; w < 64; ++w) acc[w] = NINF_PK;

    #pragma unroll 2
    for (int g = 0; g < F4C / 256; ++g) {       // 4 iterations
        int i = g * 256 + t;
        uint4  bb = bits4[i];
        float4 v0 = e4[i + 0 * (HW / 4)];
        float4 v1 = e4[i + 1 * (HW / 4)];
        float4 v2 = e4[i + 2 * (HW / 4)];
        float4 v3 = e4[i + 3 * (HW / 4)];
        float4 v4 = e4[i + 4 * (HW / 4)];
        float4 v5 = e4[i + 5 * (HW / 4)];
        float4 v6 = e4[i + 6 * (HW / 4)];
        float4 v7 = e4[i + 7 * (HW / 4)];
        DO_POS(bb.x, x)
        DO_POS(bb.y, y)
        DO_POS(bb.z, z)
        DO_POS(bb.w, w)
    }

    // ---- 2-round LDS transpose reduce over 256 threads, 32 words/round ----
    __shared__ uint32_t ldsT[256 * 33];    // padded rows: bank = (t+j)%32
    __shared__ uint32_t lds2[256];         // 8 segments x 32 words
    int blk = ((b * NCT) + ctile) * PCHUNK + chunk;

    #pragma unroll
    for (int r = 0; r < 2; ++r) {
        if (r) __syncthreads();
        #pragma unroll
        for (int j = 0; j < 32; ++j) ldsT[t * 33 + j] = acc[r * 32 + j];
        __syncthreads();
        int w = t & 31, s = t >> 5;        // 8 segments of 32 rows
        uint32_t v = ldsT[(s * 32) * 33 + w];
        #pragma unroll
        for (int k = 1; k < 32; ++k)
            v = pkmax(v, ldsT[(s * 32 + k) * 33 + w]);
        lds2[s * 32 + w] = v;
        __syncthreads();
        if (t < 32) {
            uint32_t rr = lds2[t];
            #pragma unroll
            for (int k = 1; k < 8; ++k) rr = pkmax(rr, lds2[k * 32 + t]);
            int wd = r * 32 + t;           // wd = ch*8 + mp
            partials[(size_t)blk * 128 + wd * 2 + 0] = h2f(rr & 0xFFFFu);
            partials[(size_t)blk * 128 + wd * 2 + 1] = h2f(rr >> 16);
        }
    }
}

// ---------------------------------------------------------------------------
// Kernel 3: combine PCHUNK partials per output.  out[b][c][m][1].
// ---------------------------------------------------------------------------
__global__ __launch_bounds__(256) void finalize_k(
        const float* __restrict__ partials, float* __restrict__ out) {
    int o = blockIdx.x * 256 + threadIdx.x;
    if (o >= NB * NC * NOUTM) return;
    int b = o / (NC * NOUTM);
    int r = o % (NC * NOUTM);
    int c = r / NOUTM;
    int m = r % NOUTM;
    int ctile = c >> 3, ch = c & 7;
    int mp = m >> 1, hl = m & 1;
    size_t base = (size_t)((b * NCT + ctile) * PCHUNK) * 128
                  + (ch * 8 + mp) * 2 + hl;
    float a = partials[base];
    #pragma unroll
    for (int k = 1; k < PCHUNK; ++k)
        a = fmaxf(a, partials[base + (size_t)k * 128]);
    out[o] = a;
}

extern "C" void kernel_launch(void* const* d_in, const int* in_sizes, int n_in,
                              void* d_out, int out_size, void* d_ws, size_t ws_size,
                              hipStream_t stream) {
    const float* encoded = (const float*)d_in[0];   // [8,128,128,128] f32
    const int*   masks   = (const int*)d_in[1];     // [8,16,128,128] i32
    float*       out     = (float*)d_out;           // [8,128,15,1] f32

    uint32_t* packed   = (uint32_t*)d_ws;                        // 512 KB
    float*    partials = (float*)d_ws + (size_t)NB * HW;         // 256 KB

    pack_masks_k<<<(NB * HW / 4) / 256, 256, 0, stream>>>(masks, packed);

    dim3 grid2(PCHUNK, NCT, NB);   // 4 x 16 x 8 = 512 blocks (2/CU)
    region_partial_k<<<grid2, 256, 0, stream>>>(encoded, packed, partials);

    finalize_k<<<(NB * NC * NOUTM + 255) / 256, 256, 0, stream>>>(partials, out);
}

// Round 5
// 27.162 us; speedup vs baseline: 1.5946x; 1.0338x over previous
//
#include <hip/hip_runtime.h>
#include <math.h>
#include <stdint.h>

// Problem dims (fixed): B=8, C=128, M=16, H=W=128
#define NB 8
#define NC 128
#define NM 16
#define HW (128*128)       // 16384 positions
#define NOUTM 15
#define CH 8               // channels per block
#define NCT (NC / CH)      // 16 channel tiles
#define PCHUNK 8           // position chunks -> 1024 blocks
#define F4C (HW / PCHUNK / 4)   // 512 float4/uint4 groups per chunk
#define NINF_PK 0xFC00FC00u     // packed f16 {-inf,-inf}

__device__ __forceinline__ uint32_t pkmax(uint32_t a, uint32_t b) {
    uint32_t d;
    asm("v_pk_max_f16 %0, %1, %2" : "=v"(d) : "v"(a), "v"(b));
    return d;
}
__device__ __forceinline__ uint32_t bfi(uint32_t s, uint32_t a, uint32_t b) {
    uint32_t d;
    asm("v_bfi_b32 %0, %1, %2, %3" : "=v"(d) : "v"(s), "v"(a), "v"(b));
    return d;
}
__device__ __forceinline__ uint32_t cvt_dup(float f) {
    // v_cvt_pkrtz_f16_f32: both halves = f16(f), RTZ (monotone)
    auto h = __builtin_amdgcn_cvt_pkrtz(f, f);
    return __builtin_bit_cast(uint32_t, h);
}
__device__ __forceinline__ float h2f(uint32_t h16) {
    unsigned short u = (unsigned short)h16;
    __fp16 h = __builtin_bit_cast(__fp16, u);
    return (float)h;
}
// Exact f32 atomic max via CAS (device scope; values only grow from -inf,
// so a stale initial read just costs one extra CAS iteration).
__device__ __forceinline__ void atomicMaxF(float* addr, float val) {
    int* ia = (int*)addr;
    int cur = __float_as_int(-INFINITY);
    while (__int_as_float(cur) < val) {
        int prev = atomicCAS(ia, cur, __float_as_int(val));
        if (prev == cur) break;
        cur = prev;
    }
}

// ---------------------------------------------------------------------------
// Kernel 1: pack 15 mask planes into one bitmask per (b,pos); also
// initialize out[] to -inf (stream-ordered before kernel 2; re-runs each
// replay so atomic-max into d_out stays deterministic).
// ---------------------------------------------------------------------------
__global__ __launch_bounds__(256) void pack_masks_k(
        const int* __restrict__ masks, uint32_t* __restrict__ packed,
        float* __restrict__ out) {
    int idx = blockIdx.x * 256 + threadIdx.x;   // over NB*HW = 131072
    int b   = idx >> 14;
    int pos = idx & (HW - 1);
    const int* mb = masks + (size_t)b * NM * HW + pos;
    uint32_t bits = 0u;
    #pragma unroll
    for (int m = 1; m < NM; ++m) {
        bits |= (mb[(size_t)m * HW] != 0 ? 1u : 0u) << (m - 1);
    }
    packed[idx] = bits;
    if (idx < NB * NC * NOUTM) out[idx] = -INFINITY;
}

// ---------------------------------------------------------------------------
// Kernel 2: block=(chunk,ctile,b); 8 channels x 2048 positions per block.
// Packed-f16 accumulators acc[ch*8+mp]; v_perm s01 + bfi select + pk_max.
// 2-round LDS transpose reduce, then 120 f32 atomicMax directly into out.
// ---------------------------------------------------------------------------
#define DO_POS(BW, C)                                                         \
    {                                                                         \
        uint32_t vv[8] = {cvt_dup(v0.C), cvt_dup(v1.C), cvt_dup(v2.C),        \
                          cvt_dup(v3.C), cvt_dup(v4.C), cvt_dup(v5.C),        \
                          cvt_dup(v6.C), cvt_dup(v7.C)};                      \
        uint32_t bw_ = (BW);                                                  \
        _Pragma("unroll") for (int mp = 0; mp < 8; ++mp) {                    \
            uint32_t lo = (uint32_t)((int32_t)(bw_ << (31 - 2 * mp)) >> 31);  \
            uint32_t hi = (uint32_t)((int32_t)(bw_ << (30 - 2 * mp)) >> 31);  \
            uint32_t s01 = __builtin_amdgcn_perm(hi, lo, 0x05040100u);        \
            _Pragma("unroll") for (int ch = 0; ch < 8; ++ch) {                \
                acc[ch * 8 + mp] =                                            \
                    pkmax(acc[ch * 8 + mp], bfi(s01, vv[ch], NINF_PK));       \
            }                                                                 \
        }                                                                     \
    }

__global__ __launch_bounds__(256, 3) void region_partial_k(
        const float* __restrict__ encoded,
        const uint32_t* __restrict__ packed,
        float* __restrict__ out) {
    int chunk = blockIdx.x;            // 0..PCHUNK-1
    int ctile = blockIdx.y;            // 0..NCT-1
    int b     = blockIdx.z;            // 0..NB-1
    int t     = threadIdx.x;

    const uint4*  bits4 = (const uint4*)(packed + (size_t)b * HW)
                          + (size_t)chunk * F4C;
    const float4* e4    = (const float4*)(encoded
                          + ((size_t)b * NC + (size_t)ctile * CH) * HW)
                          + (size_t)chunk * F4C;

    uint32_t acc[64];
    #pragma unroll
    for (int w = 0; w < 64; ++w) acc[w] = NINF_PK;

    #pragma unroll
    for (int g = 0; g < F4C / 256; ++g) {       // 2 iterations
        int i = g * 256 + t;
        uint4  bb = bits4[i];
        float4 v0 = e4[i + 0 * (HW / 4)];
        float4 v1 = e4[i + 1 * (HW / 4)];
        float4 v2 = e4[i + 2 * (HW / 4)];
        float4 v3 = e4[i + 3 * (HW / 4)];
        float4 v4 = e4[i + 4 * (HW / 4)];
        float4 v5 = e4[i + 5 * (HW / 4)];
        float4 v6 = e4[i + 6 * (HW / 4)];
        float4 v7 = e4[i + 7 * (HW / 4)];
        DO_POS(bb.x, x)
        DO_POS(bb.y, y)
        DO_POS(bb.z, z)
        DO_POS(bb.w, w)
    }

    // ---- 2-round LDS transpose reduce over 256 threads, 32 words/round ----
    __shared__ uint32_t ldsT[256 * 33];    // padded rows: bank = (t+j)%32
    __shared__ uint32_t lds2[256];         // 8 segments x 32 words
    __shared__ uint32_t finalw[64];

    #pragma unroll
    for (int r = 0; r < 2; ++r) {
        if (r) __syncthreads();
        #pragma unroll
        for (int j = 0; j < 32; ++j) ldsT[t * 33 + j] = acc[r * 32 + j];
        __syncthreads();
        int w = t & 31, s = t >> 5;        // 8 segments of 32 rows
        uint32_t v = ldsT[(s * 32) * 33 + w];
        #pragma unroll
        for (int k = 1; k < 32; ++k)
            v = pkmax(v, ldsT[(s * 32 + k) * 33 + w]);
        lds2[s * 32 + w] = v;
        __syncthreads();
        if (t < 32) {
            uint32_t rr = lds2[t];
            #pragma unroll
            for (int k = 1; k < 8; ++k) rr = pkmax(rr, lds2[k * 32 + t]);
            finalw[r * 32 + t] = rr;       // word index = ch*8 + mp
        }
    }
    __syncthreads();

    // 120 valid outputs: ch in [0,8), m in [0,15)
    if (t < CH * NOUTM) {
        int ch = t / NOUTM, m = t % NOUTM;
        uint32_t wv = finalw[ch * 8 + (m >> 1)];
        float f = h2f((m & 1) ? (wv >> 16) : (wv & 0xFFFFu));
        int c = ctile * CH + ch;
        atomicMaxF(out + ((size_t)b * NC + c) * NOUTM + m, f);
    }
}

extern "C" void kernel_launch(void* const* d_in, const int* in_sizes, int n_in,
                              void* d_out, int out_size, void* d_ws, size_t ws_size,
                              hipStream_t stream) {
    const float* encoded = (const float*)d_in[0];   // [8,128,128,128] f32
    const int*   masks   = (const int*)d_in[1];     // [8,16,128,128] i32
    float*       out     = (float*)d_out;           // [8,128,15,1] f32

    uint32_t* packed = (uint32_t*)d_ws;             // 512 KB

    pack_masks_k<<<(NB * HW) / 256, 256, 0, stream>>>(masks, packed, out);

    dim3 grid2(PCHUNK, NCT, NB);   // 8 x 16 x 8 = 1024 blocks (~3/CU resident)
    region_partial_k<<<grid2, 256, 0, stream>>>(encoded, packed, out);
}